// Round 6
// baseline (61.850 us; speedup 1.0000x reference)
//
#include <hip/hip_runtime.h>
#include <hip/hip_bf16.h>

#define DIM 384
#define RED 16
#define PAIR 128
#define B 2
#define M 512
#define EPSV 1e-5f
#define LSTR 133   // padded LDS row stride (floats)

typedef float f32x4 __attribute__((ext_vector_type(4)));
typedef short bf16x8 __attribute__((ext_vector_type(8)));

__device__ __forceinline__ unsigned short f2bf(float f) {
  union { float f; unsigned u; } v; v.f = f;
  unsigned r = v.u + 0x7fffu + ((v.u >> 16) & 1u);   // RTN-even
  return (unsigned short)(r >> 16);
}

// ---------------------------------------------------------------------------
// K1: 2 rows per block, 128 threads. LN (per-wave) -> xr (bf16) ->
//     T_bf[row][p][i] = bf16( sum_j xr[j] * w_out[(i*16+j)*128 + p] )
// grid = B*M/2 = 512
// ---------------------------------------------------------------------------
__global__ __launch_bounds__(128) void opm_k1(
    const float* __restrict__ x, const float* __restrict__ g,
    const float* __restrict__ be, const float* __restrict__ w_red,
    const float* __restrict__ b_red, const float* __restrict__ w_out,
    unsigned short* __restrict__ xr_bf, unsigned short* __restrict__ T_bf) {
  const int row0 = blockIdx.x * 2;
  const int tid  = threadIdx.x;
  const int wave = tid >> 6;            // 0,1 -> row row0+wave
  const int lane = tid & 63;

  __shared__ float xn_s[2][DIM];
  __shared__ float xr_s[2][RED];
  __shared__ float psum[2][4][RED];

  // ---- LayerNorm, one row per wave (xor-butterfly, no cross-wave sync) ----
  {
    const int row = row0 + wave;
    const float* xrow = x + (size_t)row * DIM;
    float v[6];
    #pragma unroll
    for (int k = 0; k < 6; ++k) v[k] = xrow[lane + 64 * k];
    float s = 0.f, sq = 0.f;
    #pragma unroll
    for (int k = 0; k < 6; ++k) { s += v[k]; sq += v[k] * v[k]; }
    #pragma unroll
    for (int off = 32; off > 0; off >>= 1) {
      s  += __shfl_xor(s, off);
      sq += __shfl_xor(sq, off);
    }
    const float mean = s * (1.0f / DIM);
    const float var  = sq * (1.0f / DIM) - mean * mean;
    const float rstd = rsqrtf(var + EPSV);
    #pragma unroll
    for (int k = 0; k < 6; ++k) {
      const int d = lane + 64 * k;
      xn_s[wave][d] = (v[k] - mean) * rstd * g[d] + be[d];
    }
  }
  __syncthreads();

  // ---- xr: 64 threads per row: r = lane&15, part = lane>>4 (4 x 96) ----
  {
    const int rw = wave, r = lane & 15, part = lane >> 4;
    const int d0 = part * 96;
    float ps = 0.f;
    #pragma unroll 4
    for (int d = d0; d < d0 + 96; ++d) ps += xn_s[rw][d] * w_red[d * RED + r];
    psum[rw][part][r] = ps;
  }
  __syncthreads();
  if (tid < 32) {
    const int rw = tid >> 4, r = tid & 15;
    float v = b_red[r];
    #pragma unroll
    for (int qq = 0; qq < 4; ++qq) v += psum[rw][qq][r];
    xr_s[rw][r] = v;
    xr_bf[(size_t)(row0 + rw) * RED + r] = f2bf(v);
  }
  __syncthreads();

  // ---- T for both rows: thread p reads each w_out element once ----
  {
    const int p = tid;  // 0..127
    const float* W = w_out + p;
    float a0[RED], a1[RED];
    #pragma unroll
    for (int i = 0; i < RED; ++i) {
      float s0 = 0.f, s1 = 0.f;
      #pragma unroll
      for (int j = 0; j < RED; ++j) {
        const float w = W[(i * RED + j) * PAIR];
        s0 += xr_s[0][j] * w;
        s1 += xr_s[1][j] * w;
      }
      a0[i] = s0; a1[i] = s1;
    }
    unsigned int* dst0 = (unsigned int*)(T_bf + ((size_t)row0 * PAIR + p) * RED);
    unsigned int* dst1 = (unsigned int*)(T_bf + ((size_t)(row0 + 1) * PAIR + p) * RED);
    #pragma unroll
    for (int k = 0; k < 8; ++k) {
      dst0[k] = (unsigned)f2bf(a0[2*k]) | ((unsigned)f2bf(a0[2*k+1]) << 16);
      dst1[k] = (unsigned)f2bf(a1[2*k]) | ((unsigned)f2bf(a1[2*k+1]) << 16);
    }
  }
}

// ---------------------------------------------------------------------------
// K2 (MFMA + LDS-transposed coalesced stores):
//   out[b,m,n,p] = b_out[p] + sum_i xr[b,m,i] * T[b,n,i,p]
// One wave per n (4 n/block). Per ms-iter (16 m): 8 MFMA -> LDS (stride 133)
// -> 256 threads emit dwordx4 stores, 1 KB contiguous per wave-instruction.
// tile = 64 m x 4 n x 128 p.  grid = B*(M/64)*(M/4) = 2048
// ---------------------------------------------------------------------------
__global__ __launch_bounds__(256) void opm_k2(
    const unsigned short* __restrict__ xr_bf, const unsigned short* __restrict__ T_bf,
    const float* __restrict__ b_out, float* __restrict__ out) {
  const int nb = blockIdx.x & 127;          // n-group (M/4 = 128)
  const int mt = (blockIdx.x >> 7) & 7;     // m-tile  (M/64 = 8)
  const int b  = blockIdx.x >> 10;
  const int tid  = threadIdx.x;
  const int wave = tid >> 6;
  const int lane = tid & 63;
  const int q = lane >> 4;                  // k-quad
  const int r = lane & 15;                  // col (p within 16-block)
  const int n = nb * 4 + wave;

  __shared__ float lds[64 * LSTR];          // [n_loc*16 + m_loc][133]

  // B fragments: bv[pb] lane(q,r) holds T[n][i=8q..8q+7][pb*16+r]; q>=2 -> 0
  bf16x8 bv[8];
  const unsigned short* Tb = T_bf + ((size_t)(b * M + n) * PAIR) * RED;
  #pragma unroll
  for (int pb = 0; pb < 8; ++pb) {
    bf16x8 v = {0, 0, 0, 0, 0, 0, 0, 0};
    if (q < 2) v = *(const bf16x8*)(Tb + (pb * 16 + r) * RED + q * 8);
    bv[pb] = v;
  }
  float bias[8];
  #pragma unroll
  for (int pb = 0; pb < 8; ++pb) bias[pb] = b_out[pb * 16 + r];

  // store-phase thread mapping
  const int inner  = tid & 127;             // 0..127 -> 2 KB row-pair span
  const int n_loc  = inner >> 5;            // 0..3
  const int p4     = (inner & 31) * 4;      // 0..124
  const int mlb    = tid >> 7;              // 0 or 1

  #pragma unroll
  for (int ms = 0; ms < 4; ++ms) {
    const int m0 = mt * 64 + ms * 16;
    // A fragment: lane(q,r) holds xr[m0+r][8q..8q+7]; q>=2 -> 0
    bf16x8 av = {0, 0, 0, 0, 0, 0, 0, 0};
    if (q < 2) av = *(const bf16x8*)(xr_bf + (size_t)(b * M + m0 + r) * RED + q * 8);

    #pragma unroll
    for (int pb = 0; pb < 8; ++pb) {
      f32x4 acc = {bias[pb], bias[pb], bias[pb], bias[pb]};
      acc = __builtin_amdgcn_mfma_f32_16x16x32_bf16(av, bv[pb], acc, 0, 0, 0);
      // D: col = r (p), row = q*4 + x  (m_loc)
      float* dst = &lds[(wave * 16 + q * 4) * LSTR + pb * 16 + r];
      dst[0]        = acc[0];
      dst[LSTR]     = acc[1];
      dst[2 * LSTR] = acc[2];
      dst[3 * LSTR] = acc[3];
    }
    __syncthreads();

    // coalesced output: each wave-instr = 1 KB contiguous (2 n-rows)
    float* ob = out + ((size_t)(b * M + m0 + mlb) * M + (nb * 4 + n_loc)) * PAIR + p4;
    #pragma unroll
    for (int ps = 0; ps < 8; ++ps) {
      const int m_loc = mlb + ps * 2;
      const f32x4 v = *(const f32x4*)&lds[(n_loc * 16 + m_loc) * LSTR + p4];
      *(f32x4*)(ob + (size_t)ps * 2 * M * PAIR) = v;
    }
    __syncthreads();
  }
}

extern "C" void kernel_launch(void* const* d_in, const int* in_sizes, int n_in,
                              void* d_out, int out_size, void* d_ws, size_t ws_size,
                              hipStream_t stream) {
  const float* x       = (const float*)d_in[0];
  const float* ln_g    = (const float*)d_in[1];
  const float* ln_b    = (const float*)d_in[2];
  const float* w_red   = (const float*)d_in[3];
  const float* b_red   = (const float*)d_in[4];
  const float* w_out   = (const float*)d_in[5];
  const float* b_out   = (const float*)d_in[6];
  float* out = (float*)d_out;

  unsigned short* xr_bf = (unsigned short*)d_ws;            // B*M*16 u16 = 32 KB
  unsigned short* T_bf  = xr_bf + (size_t)B * M * RED;      // B*M*128*16 u16 = 4 MB

  opm_k1<<<B * M / 2, 128, 0, stream>>>(x, ln_g, ln_b, w_red, b_red, w_out, xr_bf, T_bf);
  opm_k2<<<B * (M / 64) * (M / 4), 256, 0, stream>>>(xr_bf, T_bf, b_out, out);
}